// Round 1
// baseline (513.108 us; speedup 1.0000x reference)
//
#include <hip/hip_runtime.h>
#include <hip/hip_bf16.h>

#define EPS 1e-5f

typedef __attribute__((ext_vector_type(8))) short bf16x8;
typedef __attribute__((ext_vector_type(4))) float f32x4;

__device__ __forceinline__ float b2f(unsigned short u) {
  union { unsigned int i; float f; } v; v.i = ((unsigned int)u) << 16; return v.f;
}

// global -> LDS direct copy, 16B per lane. LDS dest must be wave-uniform base + lane*16.
__device__ __forceinline__ void g2l16(const void* g, void* l) {
  __builtin_amdgcn_global_load_lds(
      (__attribute__((address_space(1))) void*)((unsigned long long)g),
      (__attribute__((address_space(3))) void*)((unsigned long long)l), 16, 0, 0);
}

// ---------------- precompute kernels ----------------

// w2s[kk][oc][e'] bf16 where e' = e ^ ((oc&7)<<3)  (granule swizzle baked in)
__global__ __launch_bounds__(256) void kp_w2(const float* __restrict__ w2,
                                             __hip_bfloat16* __restrict__ w2s) {
  int g = blockIdx.x * 256 + threadIdx.x;          // 9*256*64 = 147456
  if (g >= 147456) return;
  int kk = g >> 14;
  int rem = g & 16383;
  int oc = rem >> 6, e = rem & 63;
  int es = e ^ ((oc & 7) << 3);
  float v = w2[(oc * 64 + e) * 9 + kk];            // w2[oc][ic=e][ky][kx], kk=ky*3+kx
  w2s[(kk * 256 + oc) * 64 + es] = __float2bfloat16(v);
}

// fold BN_a (pre-conv) and BN_b (post-conv) into grouped-conv weights/bias
__global__ __launch_bounds__(256) void kp_fold(
    const float* __restrict__ tw, const float* __restrict__ tb,
    const float* __restrict__ bag, const float* __restrict__ bab,
    const float* __restrict__ bam, const float* __restrict__ bav,
    const float* __restrict__ bbg, const float* __restrict__ bbb,
    const float* __restrict__ bbm, const float* __restrict__ bbv,
    float* __restrict__ wf, float* __restrict__ bfo) {
  int g = blockIdx.x * 256 + threadIdx.x;
  if (g < 18432) {                                 // [t][o8][c][3][3]
    int kk = g % 9;  (void)kk;
    int c = (g / 9) % 4;
    int o8 = (g / 36) % 8;
    int t = g / 288;
    float sa = bag[t * 4 + c] * rsqrtf(bav[t * 4 + c] + EPS);
    float sb = bbg[t * 8 + o8] * rsqrtf(bbv[t * 8 + o8] + EPS);
    wf[g] = sb * tw[g] * sa;
  }
  if (g < 512) {
    int t = g / 8;
    float sb = bbg[g] * rsqrtf(bbv[g] + EPS);
    float hb = bbb[g] - bbm[g] * sb;
    float acc = sb * tb[g] + hb;
    for (int c = 0; c < 4; c++) {
      float sa = bag[t * 4 + c] * rsqrtf(bav[t * 4 + c] + EPS);
      float ha = bab[t * 4 + c] - bam[t * 4 + c] * sa;
      float wsum = 0.f;
      for (int k = 0; k < 9; k++) wsum += tw[(g * 4 + c) * 9 + k];
      acc += sb * wsum * ha;
    }
    bfo[g] = acc;
  }
}

// compose folded grouped conv (4->8,k3) + flatten + Linear(1152->9) into
// W_eff[t][j][iy][ix][c] (iy,ix in 14x14 pooled space) and b_eff[t*9+j]
__global__ __launch_bounds__(256) void kp_weff(
    const float* __restrict__ lw, const float* __restrict__ lb,
    const float* __restrict__ wf, const float* __restrict__ bfo,
    float* __restrict__ Weff, float* __restrict__ beff) {
  int g = blockIdx.x * 256 + threadIdx.x;          // 451584
  if (g < 451584) {
    int c = g & 3;
    int pix = (g >> 2) % 196;
    int ix = pix % 14, iy = pix / 14;
    int tj = (g >> 2) / 196;                       // t*9+j
    int t = tj / 9;
    float acc = 0.f;
    for (int o8 = 0; o8 < 8; o8++) {
      const float* lwp = lw + tj * 1152 + o8 * 144;
      const float* wfp = wf + ((t * 8 + o8) * 4 + c) * 9;
      for (int ky = 0; ky < 3; ky++) {
        int y = iy - ky; if (y < 0 || y > 11) continue;
        for (int kx = 0; kx < 3; kx++) {
          int x = ix - kx; if (x < 0 || x > 11) continue;
          acc += lwp[y * 12 + x] * wfp[ky * 3 + kx];
        }
      }
    }
    Weff[g] = acc;
  }
  if (g < 576) {
    int t = g / 9;
    float acc = lb[g];
    for (int o8 = 0; o8 < 8; o8++) {
      const float* lwp = lw + g * 1152 + o8 * 144;
      float s = 0.f;
      for (int i = 0; i < 144; i++) s += lwp[i];
      acc += bfo[t * 8 + o8] * s;
    }
    beff[g] = acc;
  }
}

__global__ __launch_bounds__(256) void kp_trans(const float* __restrict__ w1, float* __restrict__ w1T,
                                                const float* __restrict__ w2, float* __restrict__ w2T) {
  int g = blockIdx.x * 256 + threadIdx.x;
  if (g < 512 * 576) { int o = g / 576, k = g % 576; w1T[k * 512 + o] = w1[g]; }
  if (g < 100 * 512) { int o = g / 512, k = g % 512; w2T[k * 100 + o] = w2[g]; }
}

// ---------------- K1: conv1 + bias + ReLU + BN1 -> h1 NHWC bf16 ----------------
__global__ __launch_bounds__(256) void k1_conv1(
    const float* __restrict__ x, const float* __restrict__ w1,
    const float* __restrict__ cb, const float* __restrict__ bg,
    const float* __restrict__ bb, const float* __restrict__ bm,
    const float* __restrict__ bv, __hip_bfloat16* __restrict__ h1) {
  __shared__ float xs[288];    // [ic][ky][32]
  __shared__ float wsm[1728];  // [oc][27]
  int tid = threadIdx.x;
  int bi = blockIdx.x;
  int b = bi / 30, y = bi % 30;
  for (int i = tid; i < 288; i += 256) {
    int ic = i / 96, ky = (i / 32) % 3, xx = i & 31;
    xs[i] = x[((b * 3 + ic) * 32 + (y + ky)) * 32 + xx];
  }
  for (int i = tid; i < 1728; i += 256) wsm[i] = w1[i];
  __syncthreads();
  int oc = tid & 63;
  int xg = tid >> 6;
  float wr[27];
#pragma unroll
  for (int q = 0; q < 27; q++) wr[q] = wsm[oc * 27 + q];
  float bias = cb[oc];
  float sc = bg[oc] * rsqrtf(bv[oc] + EPS);
  float sh = bb[oc] - bm[oc] * sc;
#pragma unroll
  for (int i = 0; i < 8; i++) {
    int xo = xg + 4 * i;
    if (xo < 30) {
      float acc = bias;
#pragma unroll
      for (int ic = 0; ic < 3; ic++)
#pragma unroll
        for (int ky = 0; ky < 3; ky++)
#pragma unroll
          for (int kx = 0; kx < 3; kx++)
            acc += xs[(ic * 3 + ky) * 32 + xo + kx] * wr[ic * 9 + ky * 3 + kx];
      acc = fmaxf(acc, 0.f);
      acc = acc * sc + sh;
      h1[(((size_t)b * 30 + y) * 30 + xo) * 64 + oc] = __float2bfloat16(acc);
    }
  }
}

// ---------------- K2: conv2 implicit GEMM + bias + ReLU + maxpool ----------------
// grid = 512*14 (b, y-pair). block 512 (8 waves, each 64M x 32N).
// M rows r = yl*28+xx (56 valid, 8 pad), N = 256 oc, K = 9 chunks x 64 ic.
__global__ __launch_bounds__(512) void k2_conv2(
    const __hip_bfloat16* __restrict__ h1, const __hip_bfloat16* __restrict__ w2s,
    const float* __restrict__ c2b, __hip_bfloat16* __restrict__ p) {
  __shared__ __align__(16) char lds[81920];  // A: 2x8KB @0, B: 2x32KB @16384
  int tid = threadIdx.x;
  int bi = blockIdx.x;
  int b = bi / 14, yp = bi % 14;
  int l = tid & 63, w = tid >> 6;

  // A staging: thread t -> row r=t/8, granule t%8; source granule pre-swizzled
  int r = tid >> 3;
  int rc = r < 56 ? r : 55;
  int yl = rc >= 28 ? 1 : 0;
  int xx = rc - yl * 28;
  int ael = ((tid & 7) << 3) ^ ((rc & 7) << 3);
  const __hip_bfloat16* aSrc0 =
      h1 + (((size_t)(b * 30 + yp * 2 + yl)) * 30 + xx) * 64 + ael;
  const char* bSrc0 = (const char*)w2s;

  f32x4 acc[4][2];
#pragma unroll
  for (int m = 0; m < 4; m++)
#pragma unroll
    for (int n = 0; n < 2; n++) acc[m][n] = (f32x4){0.f, 0.f, 0.f, 0.f};

#define STAGE(kk, s)                                                            \
  {                                                                             \
    g2l16(aSrc0 + (((kk) / 3) * 30 + ((kk) % 3)) * 64,                          \
          lds + (s)*8192 + tid * 16);                                           \
    const char* bs = bSrc0 + (kk)*32768;                                        \
    _Pragma("unroll") for (int q = 0; q < 4; q++)                               \
        g2l16(bs + q * 8192 + tid * 16,                                         \
              lds + 16384 + (s)*32768 + q * 8192 + tid * 16);                   \
  }

  STAGE(0, 0);
#pragma unroll
  for (int c = 0; c < 9; c++) {
    __syncthreads();  // loads for chunk c drained here
    if (c < 8) STAGE(c + 1, (c + 1) & 1);
    char* aB = lds + (c & 1) * 8192;
    char* bB = lds + 16384 + (c & 1) * 32768;
#pragma unroll
    for (int ks = 0; ks < 2; ks++) {
      bf16x8 af[4], bfr[2];
      int kb = (ks * 32 + ((l >> 4) * 8)) * 2;  // byte offset of k within 128B row
#pragma unroll
      for (int m = 0; m < 4; m++) {
        int row = m * 16 + (l & 15);
        af[m] = *(const bf16x8*)(aB + row * 128 + (kb ^ ((row & 7) << 4)));
      }
#pragma unroll
      for (int n = 0; n < 2; n++) {
        int oc = w * 32 + n * 16 + (l & 15);
        bfr[n] = *(const bf16x8*)(bB + oc * 128 + (kb ^ ((oc & 7) << 4)));
      }
#pragma unroll
      for (int m = 0; m < 4; m++)
#pragma unroll
        for (int n = 0; n < 2; n++)
          acc[m][n] = __builtin_amdgcn_mfma_f32_16x16x32_bf16(af[m], bfr[n], acc[m][n], 0, 0, 0);
    }
  }
#undef STAGE
  __syncthreads();  // all waves done with A/B before LDS reuse

  // epilogue: bias + ReLU -> LDS fp32 [64][33] per wave, then 2x2 maxpool
  float* ep = (float*)(lds) + w * 2112;  // 64*33 floats = 8448B per wave
#pragma unroll
  for (int n = 0; n < 2; n++) {
    int col = n * 16 + (l & 15);
    float bias = c2b[w * 32 + col];
#pragma unroll
    for (int m = 0; m < 4; m++)
#pragma unroll
      for (int i = 0; i < 4; i++) {
        int row = m * 16 + ((l >> 4) * 4) + i;  // C/D: col=l&15, row=(l>>4)*4+i
        float v = acc[m][n][i] + bias;
        ep[row * 33 + col] = fmaxf(v, 0.f);
      }
  }
  __syncthreads();
#pragma unroll
  for (int q = 0; q < 7; q++) {
    int xp = (l >> 5) * 7 + q;
    int col = l & 31;
    int base0 = (2 * xp) * 33 + col;
    float m0 = fmaxf(fmaxf(ep[base0], ep[base0 + 33]),
                     fmaxf(ep[base0 + 28 * 33], ep[base0 + 29 * 33]));
    p[(((size_t)b * 14 + yp) * 14 + xp) * 256 + w * 32 + col] = __float2bfloat16(m0);
  }
}

// ---------------- K3: towers via W_eff (einsum 'bf,tof' per tower) ----------------
__global__ __launch_bounds__(576) void k3_towers(
    const __hip_bfloat16* __restrict__ p, const float* __restrict__ Weff,
    const float* __restrict__ beff, float* __restrict__ z) {
  __shared__ __align__(16) __hip_bfloat16 pl[50176];  // 14*14*256
  int tid = threadIdx.x, b = blockIdx.x;
  const float4* src = (const float4*)(p + (size_t)b * 50176);
  float4* dst = (float4*)pl;
  for (int i = tid; i < 6272; i += 576) dst[i] = src[i];
  __syncthreads();
  int t = tid / 9;
  float acc = beff[tid];
  const float4* wrow = (const float4*)(Weff + (size_t)tid * 784);
  const __hip_bfloat16* pbase = pl + t * 4;
#pragma unroll 4
  for (int pix = 0; pix < 196; pix++) {
    float4 wv = wrow[pix];
    ushort4 pv = *(const ushort4*)(pbase + pix * 256);
    acc += wv.x * b2f(pv.x) + wv.y * b2f(pv.y) + wv.z * b2f(pv.z) + wv.w * b2f(pv.w);
  }
  z[(size_t)b * 576 + tid] = acc;
}

// ---------------- K4: FC1 + ReLU + FC2 fused, one block per batch row ----------------
__global__ __launch_bounds__(256) void k4_fc(
    const float* __restrict__ z, const float* __restrict__ w1T, const float* __restrict__ b1,
    const float* __restrict__ w2T, const float* __restrict__ b2, float* __restrict__ out) {
  __shared__ float zl[576];
  __shared__ float hl[512];
  int tid = threadIdx.x, b = blockIdx.x;
  for (int i = tid; i < 576; i += 256) zl[i] = z[(size_t)b * 576 + i];
  __syncthreads();
#pragma unroll
  for (int oo = 0; oo < 2; oo++) {
    int o = tid + oo * 256;
    float acc = b1[o];
#pragma unroll 8
    for (int k = 0; k < 576; k++) acc += zl[k] * w1T[k * 512 + o];
    hl[o] = fmaxf(acc, 0.f);
  }
  __syncthreads();
  if (tid < 100) {
    float acc = b2[tid];
#pragma unroll 8
    for (int k = 0; k < 512; k++) acc += hl[k] * w2T[k * 100 + tid];
    out[(size_t)b * 100 + tid] = acc;
  }
}

// ---------------- launch ----------------
extern "C" void kernel_launch(void* const* d_in, const int* in_sizes, int n_in,
                              void* d_out, int out_size, void* d_ws, size_t ws_size,
                              hipStream_t stream) {
  const float* x    = (const float*)d_in[0];
  const float* w1   = (const float*)d_in[1];
  const float* c1b  = (const float*)d_in[2];
  const float* bn1g = (const float*)d_in[3];
  const float* bn1b = (const float*)d_in[4];
  const float* bn1m = (const float*)d_in[5];
  const float* bn1v = (const float*)d_in[6];
  const float* w2   = (const float*)d_in[7];
  const float* c2b  = (const float*)d_in[8];
  const float* bnag = (const float*)d_in[9];
  const float* bnab = (const float*)d_in[10];
  const float* bnam = (const float*)d_in[11];
  const float* bnav = (const float*)d_in[12];
  const float* tw   = (const float*)d_in[13];
  const float* tb   = (const float*)d_in[14];
  const float* bnbg = (const float*)d_in[15];
  const float* bnbb = (const float*)d_in[16];
  const float* bnbm = (const float*)d_in[17];
  const float* bnbv = (const float*)d_in[18];
  const float* linw = (const float*)d_in[19];
  const float* linb = (const float*)d_in[20];
  const float* fc1w = (const float*)d_in[21];
  const float* fc1b = (const float*)d_in[22];
  const float* fc2w = (const float*)d_in[23];
  const float* fc2b = (const float*)d_in[24];
  float* out = (float*)d_out;

  char* ws = (char*)d_ws;
  size_t off = 0;
  auto alloc = [&](size_t bytes) {
    char* q = ws + off;
    off += (bytes + 255) & ~(size_t)255;
    return q;
  };
  __hip_bfloat16* h1  = (__hip_bfloat16*)alloc(512ull * 30 * 30 * 64 * 2);
  __hip_bfloat16* p   = (__hip_bfloat16*)alloc(512ull * 14 * 14 * 256 * 2);
  __hip_bfloat16* w2s = (__hip_bfloat16*)alloc(9ull * 256 * 64 * 2);
  float* Weff = (float*)alloc(451584ull * 4);
  float* beff = (float*)alloc(576ull * 4);
  float* wf   = (float*)alloc(18432ull * 4);
  float* bfo  = (float*)alloc(512ull * 4);
  float* w1T  = (float*)alloc(576ull * 512 * 4);
  float* w2T  = (float*)alloc(512ull * 100 * 4);
  float* z    = (float*)alloc(512ull * 576 * 4);

  kp_w2<<<576, 256, 0, stream>>>(w2, w2s);
  kp_fold<<<72, 256, 0, stream>>>(tw, tb, bnag, bnab, bnam, bnav, bnbg, bnbb, bnbm, bnbv, wf, bfo);
  kp_weff<<<1764, 256, 0, stream>>>(linw, linb, wf, bfo, Weff, beff);
  kp_trans<<<1152, 256, 0, stream>>>(fc1w, w1T, fc2w, w2T);
  k1_conv1<<<512 * 30, 256, 0, stream>>>(x, w1, c1b, bn1g, bn1b, bn1m, bn1v, h1);
  k2_conv2<<<512 * 14, 512, 0, stream>>>(h1, w2s, c2b, p);
  k3_towers<<<512, 576, 0, stream>>>(p, Weff, beff, z);
  k4_fc<<<512, 256, 0, stream>>>(z, w1T, fc1b, w2T, fc2b, out);
}

// Round 2
// 443.169 us; speedup vs baseline: 1.1578x; 1.1578x over previous
//
#include <hip/hip_runtime.h>
#include <hip/hip_bf16.h>

#define EPS 1e-5f

typedef __attribute__((ext_vector_type(8))) short bf16x8;
typedef __attribute__((ext_vector_type(4))) float f32x4;

__device__ __forceinline__ float b2f(unsigned short u) {
  union { unsigned int i; float f; } v; v.i = ((unsigned int)u) << 16; return v.f;
}
__device__ __forceinline__ unsigned short f2bu(float f) {
  __hip_bfloat16 h = __float2bfloat16(f);
  return *reinterpret_cast<unsigned short*>(&h);
}

// global -> LDS direct copy, 16B per lane. LDS dest must be wave-uniform base + lane*16.
__device__ __forceinline__ void g2l16(const void* g, void* l) {
  __builtin_amdgcn_global_load_lds(
      (__attribute__((address_space(1))) void*)((unsigned long long)g),
      (__attribute__((address_space(3))) void*)((unsigned long long)l), 16, 0, 0);
}

// ---------------- precompute kernels ----------------

// w2s[kk][oc][e'] bf16 where e' = e ^ ((oc&7)<<3)  (granule swizzle baked in)
__global__ __launch_bounds__(256) void kp_w2(const float* __restrict__ w2,
                                             __hip_bfloat16* __restrict__ w2s) {
  int g = blockIdx.x * 256 + threadIdx.x;          // 9*256*64 = 147456
  if (g >= 147456) return;
  int kk = g >> 14;
  int rem = g & 16383;
  int oc = rem >> 6, e = rem & 63;
  int es = e ^ ((oc & 7) << 3);
  float v = w2[(oc * 64 + e) * 9 + kk];            // w2[oc][ic=e][ky][kx], kk=ky*3+kx
  w2s[(kk * 256 + oc) * 64 + es] = __float2bfloat16(v);
}

// fold BN_a (pre-conv) and BN_b (post-conv) into grouped-conv weights/bias
__global__ __launch_bounds__(256) void kp_fold(
    const float* __restrict__ tw, const float* __restrict__ tb,
    const float* __restrict__ bag, const float* __restrict__ bab,
    const float* __restrict__ bam, const float* __restrict__ bav,
    const float* __restrict__ bbg, const float* __restrict__ bbb,
    const float* __restrict__ bbm, const float* __restrict__ bbv,
    float* __restrict__ wf, float* __restrict__ bfo) {
  int g = blockIdx.x * 256 + threadIdx.x;
  if (g < 18432) {                                 // [t][o8][c][3][3]
    int c = (g / 9) % 4;
    int o8 = (g / 36) % 8;
    int t = g / 288;
    float sa = bag[t * 4 + c] * rsqrtf(bav[t * 4 + c] + EPS);
    float sb = bbg[t * 8 + o8] * rsqrtf(bbv[t * 8 + o8] + EPS);
    wf[g] = sb * tw[g] * sa;
  }
  if (g < 512) {
    int t = g / 8;
    float sb = bbg[g] * rsqrtf(bbv[g] + EPS);
    float hb = bbb[g] - bbm[g] * sb;
    float acc = sb * tb[g] + hb;
    for (int c = 0; c < 4; c++) {
      float sa = bag[t * 4 + c] * rsqrtf(bav[t * 4 + c] + EPS);
      float ha = bab[t * 4 + c] - bam[t * 4 + c] * sa;
      float wsum = 0.f;
      for (int k = 0; k < 9; k++) wsum += tw[(g * 4 + c) * 9 + k];
      acc += sb * wsum * ha;
    }
    bfo[g] = acc;
  }
}

// compose folded grouped conv (4->8,k3) + flatten + Linear(1152->9) into
// W_eff[tj][pix(iy,ix)][c] (iy,ix in 14x14 pooled space) and b_eff[t*9+j]
__global__ __launch_bounds__(256) void kp_weff(
    const float* __restrict__ lw, const float* __restrict__ lb,
    const float* __restrict__ wf, const float* __restrict__ bfo,
    float* __restrict__ Weff, float* __restrict__ beff) {
  int g = blockIdx.x * 256 + threadIdx.x;          // 451584
  if (g < 451584) {
    int c = g & 3;
    int pix = (g >> 2) % 196;
    int ix = pix % 14, iy = pix / 14;
    int tj = (g >> 2) / 196;                       // t*9+j
    int t = tj / 9;
    float acc = 0.f;
    for (int o8 = 0; o8 < 8; o8++) {
      const float* lwp = lw + tj * 1152 + o8 * 144;
      const float* wfp = wf + ((t * 8 + o8) * 4 + c) * 9;
      for (int ky = 0; ky < 3; ky++) {
        int y = iy - ky; if (y < 0 || y > 11) continue;
        for (int kx = 0; kx < 3; kx++) {
          int x = ix - kx; if (x < 0 || x > 11) continue;
          acc += lwp[y * 12 + x] * wfp[ky * 3 + kx];
        }
      }
    }
    Weff[g] = acc;
  }
  if (g < 576) {
    int t = g / 9;
    float acc = lb[g];
    for (int o8 = 0; o8 < 8; o8++) {
      const float* lwp = lw + g * 1152 + o8 * 144;
      float s = 0.f;
      for (int i = 0; i < 144; i++) s += lwp[i];
      acc += bfo[t * 8 + o8] * s;
    }
    beff[g] = acc;
  }
}

// pack FC weights as bf16 pairs (k,k+1) for coalesced dword loads
__global__ __launch_bounds__(256) void kp_pack(const float* __restrict__ w1, unsigned int* __restrict__ w1p,
                                               const float* __restrict__ w2, unsigned int* __restrict__ w2p) {
  int g = blockIdx.x * 256 + threadIdx.x;
  if (g < 147456) {                                 // 288 kp x 512 o
    int kp = g >> 9, o = g & 511;
    unsigned int lo = f2bu(w1[o * 576 + 2 * kp]);
    unsigned int hi = f2bu(w1[o * 576 + 2 * kp + 1]);
    w1p[g] = lo | (hi << 16);
  }
  if (g < 25600) {                                  // 256 kp x 100 o
    int kp = g / 100, o = g % 100;
    unsigned int lo = f2bu(w2[o * 512 + 2 * kp]);
    unsigned int hi = f2bu(w2[o * 512 + 2 * kp + 1]);
    w2p[g] = lo | (hi << 16);
  }
}

// ---------------- K1: conv1 + bias + ReLU + BN1 -> h1 NHWC bf16 ----------------
// register-blocked sliding window: 27 vector LDS reads per thread (was 216 scalar)
__global__ __launch_bounds__(256) void k1_conv1(
    const float* __restrict__ x, const float* __restrict__ w1,
    const float* __restrict__ cb, const float* __restrict__ bg,
    const float* __restrict__ bb, const float* __restrict__ bm,
    const float* __restrict__ bv, __hip_bfloat16* __restrict__ h1) {
  __shared__ float xs[304];    // [ic][ky][32] (+pad for tail float4 reads)
  __shared__ float wsm[1728];  // [oc][27]
  int tid = threadIdx.x;
  int bi = blockIdx.x;
  int b = bi / 30, y = bi % 30;
  for (int i = tid; i < 288; i += 256) {
    int ic = i / 96, ky = (i / 32) % 3, xx = i & 31;
    xs[i] = x[((b * 3 + ic) * 32 + (y + ky)) * 32 + xx];
  }
  for (int i = tid; i < 1728; i += 256) wsm[i] = w1[i];
  __syncthreads();
  int oc = tid & 63;
  int xg = tid >> 6;              // 4 groups of 8 contiguous x
  float wr[27];
#pragma unroll
  for (int q = 0; q < 27; q++) wr[q] = wsm[oc * 27 + q];
  float bias = cb[oc];
  float sc = bg[oc] * rsqrtf(bv[oc] + EPS);
  float sh = bb[oc] - bm[oc] * sc;
  float o[8];
#pragma unroll
  for (int j = 0; j < 8; j++) o[j] = bias;
#pragma unroll
  for (int ic = 0; ic < 3; ic++)
#pragma unroll
    for (int ky = 0; ky < 3; ky++) {
      const float* row = xs + (ic * 3 + ky) * 32 + xg * 8;
      float4 v0 = *(const float4*)(row);
      float4 v1 = *(const float4*)(row + 4);
      float4 v2 = *(const float4*)(row + 8);
      float xv[12] = {v0.x, v0.y, v0.z, v0.w, v1.x, v1.y, v1.z, v1.w,
                      v2.x, v2.y, v2.z, v2.w};
#pragma unroll
      for (int kx = 0; kx < 3; kx++) {
        float wv = wr[ic * 9 + ky * 3 + kx];
#pragma unroll
        for (int j = 0; j < 8; j++) o[j] += xv[j + kx] * wv;
      }
    }
  int nst = (xg == 3) ? 6 : 8;
  __hip_bfloat16* dst = h1 + (((size_t)b * 30 + y) * 30 + xg * 8) * 64 + oc;
#pragma unroll
  for (int j = 0; j < 8; j++)
    if (j < nst) dst[(size_t)j * 64] = __float2bfloat16(fmaxf(o[j], 0.f) * sc + sh);
}

// ---------------- K2: conv2 implicit GEMM + bias + ReLU + maxpool -> pT ----------------
// grid = 512*14 (b, y-pair). block 512 (8 waves, each 64M x 32N).
// M rows r = yl*28+xx (56 valid, 8 pad), N = 256 oc, K = 9 chunks x 64 ic.
// output layout pT[t][b][pix][c] bf16 (plane per (t,b) = 196*4 = 784 elems = 1568B)
__global__ __launch_bounds__(512) void k2_conv2(
    const __hip_bfloat16* __restrict__ h1, const __hip_bfloat16* __restrict__ w2s,
    const float* __restrict__ c2b, __hip_bfloat16* __restrict__ pT) {
  __shared__ __align__(16) char lds[81920];  // A: 2x8KB @0, B: 2x32KB @16384
  int tid = threadIdx.x;
  int bi = blockIdx.x;
  int b = bi / 14, yp = bi % 14;
  int l = tid & 63, w = tid >> 6;

  // A staging: thread t -> row r=t/8, granule t%8; source granule pre-swizzled
  int r = tid >> 3;
  int rc = r < 56 ? r : 55;
  int yl = rc >= 28 ? 1 : 0;
  int xx = rc - yl * 28;
  int ael = ((tid & 7) << 3) ^ ((rc & 7) << 3);
  const __hip_bfloat16* aSrc0 =
      h1 + (((size_t)(b * 30 + yp * 2 + yl)) * 30 + xx) * 64 + ael;
  const char* bSrc0 = (const char*)w2s;

  f32x4 acc[4][2];
#pragma unroll
  for (int m = 0; m < 4; m++)
#pragma unroll
    for (int n = 0; n < 2; n++) acc[m][n] = (f32x4){0.f, 0.f, 0.f, 0.f};

#define STAGE(kk, s)                                                            \
  {                                                                             \
    g2l16(aSrc0 + (((kk) / 3) * 30 + ((kk) % 3)) * 64,                          \
          lds + (s)*8192 + tid * 16);                                           \
    const char* bs = bSrc0 + (kk)*32768;                                        \
    _Pragma("unroll") for (int q = 0; q < 4; q++)                               \
        g2l16(bs + q * 8192 + tid * 16,                                         \
              lds + 16384 + (s)*32768 + q * 8192 + tid * 16);                   \
  }

  STAGE(0, 0);
#pragma unroll
  for (int c = 0; c < 9; c++) {
    __syncthreads();  // loads for chunk c drained here
    if (c < 8) STAGE(c + 1, (c + 1) & 1);
    char* aB = lds + (c & 1) * 8192;
    char* bB = lds + 16384 + (c & 1) * 32768;
#pragma unroll
    for (int ks = 0; ks < 2; ks++) {
      bf16x8 af[4], bfr[2];
      int kb = (ks * 32 + ((l >> 4) * 8)) * 2;  // byte offset of k within 128B row
#pragma unroll
      for (int m = 0; m < 4; m++) {
        int row = m * 16 + (l & 15);
        af[m] = *(const bf16x8*)(aB + row * 128 + (kb ^ ((row & 7) << 4)));
      }
#pragma unroll
      for (int n = 0; n < 2; n++) {
        int oc = w * 32 + n * 16 + (l & 15);
        bfr[n] = *(const bf16x8*)(bB + oc * 128 + (kb ^ ((oc & 7) << 4)));
      }
#pragma unroll
      for (int m = 0; m < 4; m++)
#pragma unroll
        for (int n = 0; n < 2; n++)
          acc[m][n] = __builtin_amdgcn_mfma_f32_16x16x32_bf16(af[m], bfr[n], acc[m][n], 0, 0, 0);
    }
  }
#undef STAGE
  __syncthreads();  // all waves done with A/B before LDS reuse

  // epilogue: bias + ReLU -> LDS fp32 [64][33] per wave, then 2x2 maxpool
  float* ep = (float*)(lds) + w * 2112;  // 64*33 floats = 8448B per wave
#pragma unroll
  for (int n = 0; n < 2; n++) {
    int col = n * 16 + (l & 15);
    float bias = c2b[w * 32 + col];
#pragma unroll
    for (int m = 0; m < 4; m++)
#pragma unroll
      for (int i = 0; i < 4; i++) {
        int row = m * 16 + ((l >> 4) * 4) + i;  // C/D: col=l&15, row=(l>>4)*4+i
        float v = acc[m][n][i] + bias;
        ep[row * 33 + col] = fmaxf(v, 0.f);
      }
  }
  __syncthreads();
  unsigned short* pool = (unsigned short*)(lds + 69632);  // [256 ch][14 xp] bf16 bits
#pragma unroll
  for (int q = 0; q < 7; q++) {
    int xp = (l >> 5) * 7 + q;
    int col = l & 31;
    int base0 = (2 * xp) * 33 + col;
    float m0 = fmaxf(fmaxf(ep[base0], ep[base0 + 33]),
                     fmaxf(ep[base0 + 28 * 33], ep[base0 + 29 * 33]));
    pool[(w * 32 + col) * 14 + xp] = f2bu(m0);
  }
  __syncthreads();
  if (tid < 448) {                    // 64 towers x 7 chunks of 16B
    int t = tid / 7, sub = tid - t * 7;
    union { unsigned short s[8]; uint4 v; } pk;
#pragma unroll
    for (int e = 0; e < 8; e++) {
      int ee = sub * 8 + e;           // elem = pix_local*4 + c
      pk.s[e] = pool[(t * 4 + (ee & 3)) * 14 + (ee >> 2)];
    }
    *(uint4*)((char*)pT + ((size_t)(t * 512 + b)) * 1568 + yp * 112 + sub * 16) = pk.v;
  }
}

// ---------------- K3: towers z[b,tj] = sum_k pT[t][b][k] * Weff[tj][k] ----------------
// block = (t, 64-batch chunk); wave = one j (9 waves), lanes = batch.
__global__ __launch_bounds__(576) void k3_towers(
    const __hip_bfloat16* __restrict__ pT, const float* __restrict__ Weff,
    const float* __restrict__ beff, float* __restrict__ z) {
  __shared__ __align__(16) char sm[131648];
  char* Al = sm;                          // 64 rows x 1616B (padded from 1568)
  float* Wl = (float*)(sm + 103424);      // 9 x 784 f32
  int tid = threadIdx.x, bi = blockIdx.x;
  int t = bi >> 3, b0 = (bi & 7) * 64;
  for (int idx = tid; idx < 6272; idx += 576) {
    int row = idx / 98, ch = idx - row * 98;
    uint4 v = *(const uint4*)((const char*)pT + ((size_t)(t * 512 + b0 + row)) * 1568 + ch * 16);
    *(uint4*)(Al + row * 1616 + ch * 16) = v;
  }
  const uint4* wsrc = (const uint4*)(Weff + t * 9 * 784);
  for (int idx = tid; idx < 1764; idx += 576) ((uint4*)Wl)[idx] = wsrc[idx];
  __syncthreads();
  int j = tid >> 6, b = tid & 63;
  float acc = 0.f;
  const char* ap = Al + b * 1616;
  const float* wp = Wl + j * 784;
#pragma unroll 2
  for (int ch = 0; ch < 98; ch++) {
    bf16x8 pv = *(const bf16x8*)(ap + ch * 16);
    float4 w0 = *(const float4*)(wp + ch * 8);
    float4 w1_ = *(const float4*)(wp + ch * 8 + 4);
    acc += b2f((unsigned short)pv[0]) * w0.x + b2f((unsigned short)pv[1]) * w0.y +
           b2f((unsigned short)pv[2]) * w0.z + b2f((unsigned short)pv[3]) * w0.w +
           b2f((unsigned short)pv[4]) * w1_.x + b2f((unsigned short)pv[5]) * w1_.y +
           b2f((unsigned short)pv[6]) * w1_.z + b2f((unsigned short)pv[7]) * w1_.w;
  }
  z[(size_t)(b0 + b) * 576 + t * 9 + j] = acc + beff[t * 9 + j];
}

// ---------------- K4: FC1 + ReLU + FC2 fused, one block per batch row ----------------
__global__ __launch_bounds__(256) void k4_fc(
    const float* __restrict__ z, const unsigned int* __restrict__ w1p, const float* __restrict__ b1,
    const unsigned int* __restrict__ w2p, const float* __restrict__ b2, float* __restrict__ out) {
  __shared__ float zl[576];
  __shared__ float hl[512];
  int tid = threadIdx.x, b = blockIdx.x;
  for (int i = tid; i < 576; i += 256) zl[i] = z[(size_t)b * 576 + i];
  __syncthreads();
#pragma unroll
  for (int oo = 0; oo < 2; oo++) {
    int o = tid + oo * 256;
    float acc = b1[o];
#pragma unroll 4
    for (int kp = 0; kp < 288; kp++) {
      unsigned int u = w1p[kp * 512 + o];
      float2 zz = *(const float2*)(zl + 2 * kp);
      acc += zz.x * b2f((unsigned short)(u & 0xffff)) + zz.y * b2f((unsigned short)(u >> 16));
    }
    hl[o] = fmaxf(acc, 0.f);
  }
  __syncthreads();
  if (tid < 100) {
    float acc = b2[tid];
#pragma unroll 4
    for (int kp = 0; kp < 256; kp++) {
      unsigned int u = w2p[kp * 100 + tid];
      float2 hh = *(const float2*)(hl + 2 * kp);
      acc += hh.x * b2f((unsigned short)(u & 0xffff)) + hh.y * b2f((unsigned short)(u >> 16));
    }
    out[(size_t)b * 100 + tid] = acc;
  }
}

// ---------------- launch ----------------
extern "C" void kernel_launch(void* const* d_in, const int* in_sizes, int n_in,
                              void* d_out, int out_size, void* d_ws, size_t ws_size,
                              hipStream_t stream) {
  const float* x    = (const float*)d_in[0];
  const float* w1   = (const float*)d_in[1];
  const float* c1b  = (const float*)d_in[2];
  const float* bn1g = (const float*)d_in[3];
  const float* bn1b = (const float*)d_in[4];
  const float* bn1m = (const float*)d_in[5];
  const float* bn1v = (const float*)d_in[6];
  const float* w2   = (const float*)d_in[7];
  const float* c2b  = (const float*)d_in[8];
  const float* bnag = (const float*)d_in[9];
  const float* bnab = (const float*)d_in[10];
  const float* bnam = (const float*)d_in[11];
  const float* bnav = (const float*)d_in[12];
  const float* tw   = (const float*)d_in[13];
  const float* tb   = (const float*)d_in[14];
  const float* bnbg = (const float*)d_in[15];
  const float* bnbb = (const float*)d_in[16];
  const float* bnbm = (const float*)d_in[17];
  const float* bnbv = (const float*)d_in[18];
  const float* linw = (const float*)d_in[19];
  const float* linb = (const float*)d_in[20];
  const float* fc1w = (const float*)d_in[21];
  const float* fc1b = (const float*)d_in[22];
  const float* fc2w = (const float*)d_in[23];
  const float* fc2b = (const float*)d_in[24];
  float* out = (float*)d_out;

  char* ws = (char*)d_ws;
  size_t off = 0;
  auto alloc = [&](size_t bytes) {
    char* q = ws + off;
    off += (bytes + 255) & ~(size_t)255;
    return q;
  };
  __hip_bfloat16* h1  = (__hip_bfloat16*)alloc(512ull * 30 * 30 * 64 * 2);
  __hip_bfloat16* pT  = (__hip_bfloat16*)alloc(64ull * 512 * 784 * 2 + 256);
  __hip_bfloat16* w2s = (__hip_bfloat16*)alloc(9ull * 256 * 64 * 2);
  float* Weff = (float*)alloc(451584ull * 4);
  float* beff = (float*)alloc(576ull * 4);
  float* wf   = (float*)alloc(18432ull * 4);
  float* bfo  = (float*)alloc(512ull * 4);
  unsigned int* w1p = (unsigned int*)alloc(288ull * 512 * 4);
  unsigned int* w2p = (unsigned int*)alloc(256ull * 100 * 4);
  float* z    = (float*)alloc(512ull * 576 * 4);

  kp_w2<<<576, 256, 0, stream>>>(w2, w2s);
  kp_fold<<<72, 256, 0, stream>>>(tw, tb, bnag, bnab, bnam, bnav, bnbg, bnbb, bnbm, bnbv, wf, bfo);
  kp_weff<<<1764, 256, 0, stream>>>(linw, linb, wf, bfo, Weff, beff);
  kp_pack<<<576, 256, 0, stream>>>(fc1w, w1p, fc2w, w2p);
  k1_conv1<<<512 * 30, 256, 0, stream>>>(x, w1, c1b, bn1g, bn1b, bn1m, bn1v, h1);
  k2_conv2<<<512 * 14, 512, 0, stream>>>(h1, w2s, c2b, pT);
  k3_towers<<<512, 576, 0, stream>>>(pT, Weff, beff, z);
  k4_fc<<<512, 256, 0, stream>>>(z, w1p, fc1b, w2p, fc2b, out);
}

// Round 3
// 438.692 us; speedup vs baseline: 1.1696x; 1.0102x over previous
//
#include <hip/hip_runtime.h>
#include <hip/hip_bf16.h>

#define EPS 1e-5f

typedef __attribute__((ext_vector_type(8))) short bf16x8;
typedef __attribute__((ext_vector_type(4))) float f32x4;

__device__ __forceinline__ float b2f(unsigned short u) {
  union { unsigned int i; float f; } v; v.i = ((unsigned int)u) << 16; return v.f;
}
__device__ __forceinline__ unsigned short f2bu(float f) {
  __hip_bfloat16 h = __float2bfloat16(f);
  return *reinterpret_cast<unsigned short*>(&h);
}

// global -> LDS direct copy, 16B per lane. LDS dest must be wave-uniform base + lane*16.
__device__ __forceinline__ void g2l16(const void* g, void* l) {
  __builtin_amdgcn_global_load_lds(
      (__attribute__((address_space(1))) void*)((unsigned long long)g),
      (__attribute__((address_space(3))) void*)((unsigned long long)l), 16, 0, 0);
}

// ---------------- K_prep: fused {conv1+BN, w2 swizzle-pack, FC pack, Weff+fold} ----------------
// blockIdx ranges: [0,15360) conv1 | [15360,15936) w2s | [15936,16512) fc-pack | [16512,18276) Weff
__global__ __launch_bounds__(256) void k_prep(
    const float* __restrict__ x, const float* __restrict__ w1,
    const float* __restrict__ cb, const float* __restrict__ bg,
    const float* __restrict__ bb, const float* __restrict__ bm,
    const float* __restrict__ bv, __hip_bfloat16* __restrict__ h1,
    const float* __restrict__ w2, __hip_bfloat16* __restrict__ w2s,
    const float* __restrict__ fw1, unsigned int* __restrict__ w1p,
    const float* __restrict__ fw2, unsigned int* __restrict__ w2p,
    const float* __restrict__ lw, const float* __restrict__ lb,
    const float* __restrict__ tw, const float* __restrict__ tb,
    const float* __restrict__ bag, const float* __restrict__ bab,
    const float* __restrict__ bam, const float* __restrict__ bav,
    const float* __restrict__ bbg, const float* __restrict__ bbb,
    const float* __restrict__ bbm, const float* __restrict__ bbv,
    float* __restrict__ Weff, float* __restrict__ beff) {
  __shared__ float xs[304];
  __shared__ float wsm[1728];
  int tid = threadIdx.x;
  int bi = blockIdx.x;

  if (bi < 15360) {
    // -------- conv1 + bias + ReLU + BN1 -> h1 NHWC bf16 --------
    int b = bi / 30, y = bi % 30;
    for (int i = tid; i < 288; i += 256) {
      int ic = i / 96, ky = (i / 32) % 3, xx = i & 31;
      xs[i] = x[((b * 3 + ic) * 32 + (y + ky)) * 32 + xx];
    }
    for (int i = tid; i < 1728; i += 256) wsm[i] = w1[i];
    __syncthreads();
    int oc = tid & 63;
    int xg = tid >> 6;
    float wr[27];
#pragma unroll
    for (int q = 0; q < 27; q++) wr[q] = wsm[oc * 27 + q];
    float bias = cb[oc];
    float sc = bg[oc] * rsqrtf(bv[oc] + EPS);
    float sh = bb[oc] - bm[oc] * sc;
    float o[8];
#pragma unroll
    for (int j = 0; j < 8; j++) o[j] = bias;
#pragma unroll
    for (int ic = 0; ic < 3; ic++)
#pragma unroll
      for (int ky = 0; ky < 3; ky++) {
        const float* row = xs + (ic * 3 + ky) * 32 + xg * 8;
        float4 v0 = *(const float4*)(row);
        float4 v1 = *(const float4*)(row + 4);
        float4 v2 = *(const float4*)(row + 8);
        float xv[12] = {v0.x, v0.y, v0.z, v0.w, v1.x, v1.y, v1.z, v1.w,
                        v2.x, v2.y, v2.z, v2.w};
#pragma unroll
        for (int kx = 0; kx < 3; kx++) {
          float wv = wr[ic * 9 + ky * 3 + kx];
#pragma unroll
          for (int j = 0; j < 8; j++) o[j] += xv[j + kx] * wv;
        }
      }
    int nst = (xg == 3) ? 6 : 8;
    __hip_bfloat16* dst = h1 + (((size_t)b * 30 + y) * 30 + xg * 8) * 64 + oc;
#pragma unroll
    for (int j = 0; j < 8; j++)
      if (j < nst) dst[(size_t)j * 64] = __float2bfloat16(fmaxf(o[j], 0.f) * sc + sh);
  } else if (bi < 15936) {
    // -------- w2s[kk][oc][e'] bf16, e' = e ^ ((oc&7)<<3) --------
    int g = (bi - 15360) * 256 + tid;            // < 147456
    int kk = g >> 14;
    int rem = g & 16383;
    int oc = rem >> 6, e = rem & 63;
    int es = e ^ ((oc & 7) << 3);
    w2s[(kk * 256 + oc) * 64 + es] = __float2bfloat16(w2[(oc * 64 + e) * 9 + kk]);
  } else if (bi < 16512) {
    // -------- FC weight bf16 pair packing --------
    int g = (bi - 15936) * 256 + tid;
    {                                            // 288 kp x 512 o
      int kp = g >> 9, o = g & 511;
      unsigned int lo = f2bu(fw1[o * 576 + 2 * kp]);
      unsigned int hi = f2bu(fw1[o * 576 + 2 * kp + 1]);
      w1p[g] = lo | (hi << 16);
    }
    if (g < 25600) {                             // 256 kp x 100 o
      int kp = g / 100, o = g % 100;
      unsigned int lo = f2bu(fw2[o * 512 + 2 * kp]);
      unsigned int hi = f2bu(fw2[o * 512 + 2 * kp + 1]);
      w2p[g] = lo | (hi << 16);
    }
  } else {
    // -------- Weff / beff with inline BN-fold --------
    int g = (bi - 16512) * 256 + tid;
    if (g < 451584) {
      int c = g & 3;
      int pix = (g >> 2) % 196;
      int ix = pix % 14, iy = pix / 14;
      int tj = (g >> 2) / 196;
      int t = tj / 9;
      float sa = bag[t * 4 + c] * rsqrtf(bav[t * 4 + c] + EPS);
      float acc = 0.f;
      for (int o8 = 0; o8 < 8; o8++) {
        float sb = bbg[t * 8 + o8] * rsqrtf(bbv[t * 8 + o8] + EPS);
        const float* lwp = lw + tj * 1152 + o8 * 144;
        const float* twp = tw + ((t * 8 + o8) * 4 + c) * 9;
        float a8 = 0.f;
        for (int ky = 0; ky < 3; ky++) {
          int y = iy - ky; if (y < 0 || y > 11) continue;
          for (int kx = 0; kx < 3; kx++) {
            int xq = ix - kx; if (xq < 0 || xq > 11) continue;
            a8 += lwp[y * 12 + xq] * twp[ky * 3 + kx];
          }
        }
        acc += sb * a8;
      }
      Weff[g] = acc * sa;
    }
    if (g < 576) {
      int t = g / 9;
      float acc = lb[g];
      for (int o8 = 0; o8 < 8; o8++) {
        float sb = bbg[t * 8 + o8] * rsqrtf(bbv[t * 8 + o8] + EPS);
        float bfov = sb * tb[t * 8 + o8] + bbb[t * 8 + o8] - bbm[t * 8 + o8] * sb;
        for (int c2 = 0; c2 < 4; c2++) {
          float sa2 = bag[t * 4 + c2] * rsqrtf(bav[t * 4 + c2] + EPS);
          float ha = bab[t * 4 + c2] - bam[t * 4 + c2] * sa2;
          float wsum = 0.f;
          for (int k = 0; k < 9; k++) wsum += tw[((t * 8 + o8) * 4 + c2) * 9 + k];
          bfov += sb * wsum * ha;
        }
        float s144 = 0.f;
        const float* lwp = lw + g * 1152 + o8 * 144;
        for (int i = 0; i < 144; i++) s144 += lwp[i];
        acc += bfov * s144;
      }
      beff[g] = acc;
    }
  }
}

// ---------------- K2: conv2 implicit GEMM + bias + ReLU + maxpool -> pT ----------------
// grid = 512*14 (b, y-pair). block 256 (4 waves, each 64M x 64N).
// M rows r = yl*28+xx (56 valid, 8 pad), N = 256 oc, K = 9 chunks x 64 ic.
__global__ __launch_bounds__(256, 2) void k2_conv2(
    const __hip_bfloat16* __restrict__ h1, const __hip_bfloat16* __restrict__ w2s,
    const float* __restrict__ c2b, __hip_bfloat16* __restrict__ pT) {
  __shared__ __align__(16) char lds[81920];  // A: 2x8KB @0, B: 2x32KB @16384
  int tid = threadIdx.x;
  int bi = blockIdx.x;
  int b = bi / 14, yp = bi % 14;
  int l = tid & 63, w = tid >> 6;

  // A staging: 2 insts/thread; inst i covers granule g = w*128 + i*64 + l
  const __hip_bfloat16* aS[2];
  int cg = l & 7;
#pragma unroll
  for (int i = 0; i < 2; i++) {
    int r = w * 16 + i * 8 + (l >> 3);
    int rc = r < 56 ? r : 55;
    int yl = rc >= 28 ? 1 : 0;
    int xx = rc - yl * 28;
    int ael = (cg << 3) ^ ((rc & 7) << 3);   // pre-swizzled source granule
    aS[i] = h1 + (((size_t)(b * 30 + yp * 2 + yl)) * 30 + xx) * 64 + ael;
  }
  const char* bSrc0 = (const char*)w2s;

  f32x4 acc[4][4];
#pragma unroll
  for (int m = 0; m < 4; m++)
#pragma unroll
    for (int n = 0; n < 4; n++) acc[m][n] = (f32x4){0.f, 0.f, 0.f, 0.f};

#define STAGE(kk, s)                                                            \
  {                                                                             \
    _Pragma("unroll") for (int i = 0; i < 2; i++)                               \
        g2l16(aS[i] + (((kk) / 3) * 30 + ((kk) % 3)) * 64,                      \
              lds + (s)*8192 + w * 2048 + i * 1024 + l * 16);                   \
    const char* bs = bSrc0 + (kk)*32768;                                        \
    _Pragma("unroll") for (int q = 0; q < 8; q++)                               \
        g2l16(bs + q * 4096 + tid * 16,                                         \
              lds + 16384 + (s)*32768 + q * 4096 + tid * 16);                   \
  }

  STAGE(0, 0);
#pragma unroll
  for (int c = 0; c < 9; c++) {
    __syncthreads();  // loads for chunk c drained here
    if (c < 8) STAGE(c + 1, (c + 1) & 1);
    char* aB = lds + (c & 1) * 8192;
    char* bB = lds + 16384 + (c & 1) * 32768;
#pragma unroll
    for (int ks = 0; ks < 2; ks++) {
      bf16x8 af[4], bfr[4];
      int kb = (ks * 32 + ((l >> 4) * 8)) * 2;  // byte offset of k within 128B row
#pragma unroll
      for (int m = 0; m < 4; m++) {
        int row = m * 16 + (l & 15);
        af[m] = *(const bf16x8*)(aB + row * 128 + (kb ^ ((row & 7) << 4)));
      }
#pragma unroll
      for (int n = 0; n < 4; n++) {
        int oc = w * 64 + n * 16 + (l & 15);
        bfr[n] = *(const bf16x8*)(bB + oc * 128 + (kb ^ ((oc & 7) << 4)));
      }
#pragma unroll
      for (int m = 0; m < 4; m++)
#pragma unroll
        for (int n = 0; n < 4; n++)
          acc[m][n] = __builtin_amdgcn_mfma_f32_16x16x32_bf16(af[m], bfr[n], acc[m][n], 0, 0, 0);
    }
  }
#undef STAGE
  __syncthreads();  // all waves done with A/B before LDS reuse

  // epilogue: bias + ReLU -> LDS fp32 [64 rows][65] per wave (cols w*64..+64)
  float* ep = (float*)lds + w * 4160;
#pragma unroll
  for (int n = 0; n < 4; n++) {
    int col = n * 16 + (l & 15);
    float bias = c2b[w * 64 + col];
#pragma unroll
    for (int m = 0; m < 4; m++)
#pragma unroll
      for (int i = 0; i < 4; i++) {
        int row = m * 16 + ((l >> 4) * 4) + i;  // C/D: col=l&15, row=(l>>4)*4+i
        ep[row * 65 + col] = fmaxf(acc[m][n][i] + bias, 0.f);
      }
  }
  __syncthreads();
  unsigned short* pool = (unsigned short*)(lds + 66560);  // [256 ch][14 xp] bf16 bits
#pragma unroll
  for (int xp = 0; xp < 14; xp++) {
    int base0 = (2 * xp) * 65 + l;
    float m0 = fmaxf(fmaxf(ep[base0], ep[base0 + 65]),
                     fmaxf(ep[base0 + 28 * 65], ep[base0 + 29 * 65]));
    pool[(w * 64 + l) * 14 + xp] = f2bu(m0);
  }
  __syncthreads();
  for (int wi = tid; wi < 448; wi += 256) {   // 64 towers x 7 chunks of 16B
    int t = wi / 7, sub = wi - t * 7;
    union { unsigned short s[8]; uint4 v; } pk;
#pragma unroll
    for (int e = 0; e < 8; e++) {
      int ee = sub * 8 + e;                   // elem = pix_local*4 + c
      pk.s[e] = pool[(t * 4 + (ee & 3)) * 14 + (ee >> 2)];
    }
    *(uint4*)((char*)pT + ((size_t)(t * 512 + b)) * 1568 + yp * 112 + sub * 16) = pk.v;
  }
}

// ---------------- K3: towers z[b,tj] = sum_k pT[t][b][k] * Weff[tj][k] ----------------
__global__ __launch_bounds__(576) void k3_towers(
    const __hip_bfloat16* __restrict__ pT, const float* __restrict__ Weff,
    const float* __restrict__ beff, float* __restrict__ z) {
  __shared__ __align__(16) char sm[131648];
  char* Al = sm;                          // 64 rows x 1616B (padded from 1568)
  float* Wl = (float*)(sm + 103424);      // 9 x 784 f32
  int tid = threadIdx.x, bi = blockIdx.x;
  int t = bi >> 3, b0 = (bi & 7) * 64;
  for (int idx = tid; idx < 6272; idx += 576) {
    int row = idx / 98, ch = idx - row * 98;
    uint4 v = *(const uint4*)((const char*)pT + ((size_t)(t * 512 + b0 + row)) * 1568 + ch * 16);
    *(uint4*)(Al + row * 1616 + ch * 16) = v;
  }
  const uint4* wsrc = (const uint4*)(Weff + t * 9 * 784);
  for (int idx = tid; idx < 1764; idx += 576) ((uint4*)Wl)[idx] = wsrc[idx];
  __syncthreads();
  int j = tid >> 6, b = tid & 63;
  float acc = 0.f;
  const char* ap = Al + b * 1616;
  const float* wp = Wl + j * 784;
#pragma unroll 2
  for (int ch = 0; ch < 98; ch++) {
    bf16x8 pv = *(const bf16x8*)(ap + ch * 16);
    float4 w0 = *(const float4*)(wp + ch * 8);
    float4 w1_ = *(const float4*)(wp + ch * 8 + 4);
    acc += b2f((unsigned short)pv[0]) * w0.x + b2f((unsigned short)pv[1]) * w0.y +
           b2f((unsigned short)pv[2]) * w0.z + b2f((unsigned short)pv[3]) * w0.w +
           b2f((unsigned short)pv[4]) * w1_.x + b2f((unsigned short)pv[5]) * w1_.y +
           b2f((unsigned short)pv[6]) * w1_.z + b2f((unsigned short)pv[7]) * w1_.w;
  }
  z[(size_t)(b0 + b) * 576 + t * 9 + j] = acc + beff[t * 9 + j];
}

// ---------------- K4: FC1 + ReLU + FC2 fused, one block per batch row ----------------
__global__ __launch_bounds__(256) void k4_fc(
    const float* __restrict__ z, const unsigned int* __restrict__ w1p, const float* __restrict__ b1,
    const unsigned int* __restrict__ w2p, const float* __restrict__ b2, float* __restrict__ out) {
  __shared__ float zl[576];
  __shared__ float hl[512];
  int tid = threadIdx.x, b = blockIdx.x;
  for (int i = tid; i < 576; i += 256) zl[i] = z[(size_t)b * 576 + i];
  __syncthreads();
#pragma unroll
  for (int oo = 0; oo < 2; oo++) {
    int o = tid + oo * 256;
    float acc = b1[o];
#pragma unroll 4
    for (int kp = 0; kp < 288; kp++) {
      unsigned int u = w1p[kp * 512 + o];
      float2 zz = *(const float2*)(zl + 2 * kp);
      acc += zz.x * b2f((unsigned short)(u & 0xffff)) + zz.y * b2f((unsigned short)(u >> 16));
    }
    hl[o] = fmaxf(acc, 0.f);
  }
  __syncthreads();
  if (tid < 100) {
    float acc = b2[tid];
#pragma unroll 4
    for (int kp = 0; kp < 256; kp++) {
      unsigned int u = w2p[kp * 100 + tid];
      float2 hh = *(const float2*)(hl + 2 * kp);
      acc += hh.x * b2f((unsigned short)(u & 0xffff)) + hh.y * b2f((unsigned short)(u >> 16));
    }
    out[(size_t)b * 100 + tid] = acc;
  }
}

// ---------------- launch ----------------
extern "C" void kernel_launch(void* const* d_in, const int* in_sizes, int n_in,
                              void* d_out, int out_size, void* d_ws, size_t ws_size,
                              hipStream_t stream) {
  const float* x    = (const float*)d_in[0];
  const float* w1   = (const float*)d_in[1];
  const float* c1b  = (const float*)d_in[2];
  const float* bn1g = (const float*)d_in[3];
  const float* bn1b = (const float*)d_in[4];
  const float* bn1m = (const float*)d_in[5];
  const float* bn1v = (const float*)d_in[6];
  const float* w2   = (const float*)d_in[7];
  const float* c2b  = (const float*)d_in[8];
  const float* bnag = (const float*)d_in[9];
  const float* bnab = (const float*)d_in[10];
  const float* bnam = (const float*)d_in[11];
  const float* bnav = (const float*)d_in[12];
  const float* tw   = (const float*)d_in[13];
  const float* tb   = (const float*)d_in[14];
  const float* bnbg = (const float*)d_in[15];
  const float* bnbb = (const float*)d_in[16];
  const float* bnbm = (const float*)d_in[17];
  const float* bnbv = (const float*)d_in[18];
  const float* linw = (const float*)d_in[19];
  const float* linb = (const float*)d_in[20];
  const float* fc1w = (const float*)d_in[21];
  const float* fc1b = (const float*)d_in[22];
  const float* fc2w = (const float*)d_in[23];
  const float* fc2b = (const float*)d_in[24];
  float* out = (float*)d_out;

  char* ws = (char*)d_ws;
  size_t off = 0;
  auto alloc = [&](size_t bytes) {
    char* q = ws + off;
    off += (bytes + 255) & ~(size_t)255;
    return q;
  };
  __hip_bfloat16* h1  = (__hip_bfloat16*)alloc(512ull * 30 * 30 * 64 * 2);
  __hip_bfloat16* pT  = (__hip_bfloat16*)alloc(64ull * 512 * 784 * 2 + 256);
  __hip_bfloat16* w2s = (__hip_bfloat16*)alloc(9ull * 256 * 64 * 2);
  float* Weff = (float*)alloc(451584ull * 4);
  float* beff = (float*)alloc(576ull * 4);
  unsigned int* w1p = (unsigned int*)alloc(288ull * 512 * 4);
  unsigned int* w2p = (unsigned int*)alloc(256ull * 100 * 4);
  float* z    = (float*)alloc(512ull * 576 * 4);

  k_prep<<<18276, 256, 0, stream>>>(x, w1, c1b, bn1g, bn1b, bn1m, bn1v, h1,
                                    w2, w2s, fc1w, w1p, fc2w, w2p,
                                    linw, linb, tw, tb,
                                    bnag, bnab, bnam, bnav,
                                    bnbg, bnbb, bnbm, bnbv, Weff, beff);
  k2_conv2<<<512 * 14, 256, 0, stream>>>(h1, w2s, c2b, pT);
  k3_towers<<<512, 576, 0, stream>>>(pT, Weff, beff, z);
  k4_fc<<<512, 256, 0, stream>>>(z, w1p, fc1b, w2p, fc2b, out);
}

// Round 4
// 371.289 us; speedup vs baseline: 1.3820x; 1.1815x over previous
//
#include <hip/hip_runtime.h>
#include <hip/hip_bf16.h>

#define EPS 1e-5f

typedef __attribute__((ext_vector_type(8))) short bf16x8;
typedef __attribute__((ext_vector_type(4))) float f32x4;

__device__ __forceinline__ float b2f(unsigned short u) {
  union { unsigned int i; float f; } v; v.i = ((unsigned int)u) << 16; return v.f;
}
__device__ __forceinline__ unsigned short f2bu(float f) {
  __hip_bfloat16 h = __float2bfloat16(f);
  return *reinterpret_cast<unsigned short*>(&h);
}

// global -> LDS direct copy, 16B per lane. LDS dest must be wave-uniform base + lane*16.
__device__ __forceinline__ void g2l16(const void* g, void* l) {
  __builtin_amdgcn_global_load_lds(
      (__attribute__((address_space(1))) void*)((unsigned long long)g),
      (__attribute__((address_space(3))) void*)((unsigned long long)l), 16, 0, 0);
}

// ---------------- K_prep: fused {Weff+beff, conv1+BN, w2 swizzle, FC pack} ----------------
// blockIdx: [0,64) Weff | [64,576) conv1 | [576,1152) w2s | [1152,1728) fc-pack
__global__ __launch_bounds__(256) void k_prep(
    const float* __restrict__ x, const float* __restrict__ w1,
    const float* __restrict__ cb, const float* __restrict__ bg,
    const float* __restrict__ bb, const float* __restrict__ bm,
    const float* __restrict__ bv, __hip_bfloat16* __restrict__ h1,
    const float* __restrict__ w2, __hip_bfloat16* __restrict__ w2s,
    const float* __restrict__ fw1, unsigned int* __restrict__ w1p,
    const float* __restrict__ fw2, unsigned int* __restrict__ w2p,
    const float* __restrict__ lw, const float* __restrict__ lb,
    const float* __restrict__ tw, const float* __restrict__ tb,
    const float* __restrict__ bag, const float* __restrict__ bab,
    const float* __restrict__ bam, const float* __restrict__ bav,
    const float* __restrict__ bbg, const float* __restrict__ bbb,
    const float* __restrict__ bbm, const float* __restrict__ bbv,
    float* __restrict__ Weff, float* __restrict__ beff) {
  __shared__ __align__(16) char smem[43008];
  int tid = threadIdx.x;
  int bi = blockIdx.x;

  if (bi < 64) {
    // -------- Weff/beff for tower t: all reads staged/coalesced --------
    int t = bi;
    float* lws = (float*)smem;            // [9][1152]
    float* tws = (float*)(smem + 41472);  // [8][4][9] BN-folded
    float* part = (float*)(smem + 42624); // [9][8] beff partials
    {
      const float4* src = (const float4*)(lw + (size_t)t * 9 * 1152);
      float4* dst = (float4*)lws;
      for (int i = tid; i < 2592; i += 256) dst[i] = src[i];
    }
    for (int i = tid; i < 288; i += 256) {
      int o8 = i / 36, c = (i % 36) / 9, kk = i % 9;
      float sa = bag[t * 4 + c] * rsqrtf(bav[t * 4 + c] + EPS);
      float sb = bbg[t * 8 + o8] * rsqrtf(bbv[t * 8 + o8] + EPS);
      tws[i] = tw[((t * 8 + o8) * 4 + c) * 9 + kk] * sa * sb;
    }
    __syncthreads();
    if (tid < 252) {
      int j = tid / 28;
      int rem = tid % 28;
      int c = rem / 7, q = rem % 7;     // output rows 2q, 2q+1
      float acc[2][14];
#pragma unroll
      for (int pr = 0; pr < 2; pr++)
#pragma unroll
        for (int ix = 0; ix < 14; ix++) acc[pr][ix] = 0.f;
#pragma unroll 1
      for (int o8 = 0; o8 < 8; o8++) {
        float twr[9];
#pragma unroll
        for (int kk = 0; kk < 9; kk++) twr[kk] = tws[o8 * 36 + c * 9 + kk];
        float lwc[4][16];
#pragma unroll
        for (int cr = 0; cr < 4; cr++) {
          int y = 2 * q - 2 + cr;
          bool vld = (y >= 0) & (y <= 11);
          int ya = vld ? y : 0;
          const float* bp = lws + j * 1152 + o8 * 144 + ya * 12;
          float4 A = *(const float4*)bp;
          float4 B = *(const float4*)(bp + 4);
          float4 C = *(const float4*)(bp + 8);
          lwc[cr][0] = 0.f; lwc[cr][1] = 0.f; lwc[cr][14] = 0.f; lwc[cr][15] = 0.f;
          lwc[cr][2] = vld ? A.x : 0.f;  lwc[cr][3] = vld ? A.y : 0.f;
          lwc[cr][4] = vld ? A.z : 0.f;  lwc[cr][5] = vld ? A.w : 0.f;
          lwc[cr][6] = vld ? B.x : 0.f;  lwc[cr][7] = vld ? B.y : 0.f;
          lwc[cr][8] = vld ? B.z : 0.f;  lwc[cr][9] = vld ? B.w : 0.f;
          lwc[cr][10] = vld ? C.x : 0.f; lwc[cr][11] = vld ? C.y : 0.f;
          lwc[cr][12] = vld ? C.z : 0.f; lwc[cr][13] = vld ? C.w : 0.f;
        }
#pragma unroll
        for (int ky = 0; ky < 3; ky++)
#pragma unroll
          for (int kx = 0; kx < 3; kx++) {
            float wv = twr[ky * 3 + kx];
#pragma unroll
            for (int pr = 0; pr < 2; pr++)
#pragma unroll
              for (int ix = 0; ix < 14; ix++)
                acc[pr][ix] += lwc[pr - ky + 2][ix - kx + 2] * wv;
          }
      }
#pragma unroll
      for (int pr = 0; pr < 2; pr++)
#pragma unroll
        for (int ix = 0; ix < 14; ix++)
          Weff[(((size_t)(t * 9 + j)) * 196 + (2 * q + pr) * 14 + ix) * 4 + c] = acc[pr][ix];
    }
    // beff partials: thread (j,o8)
    if (tid < 72) {
      int j = tid / 8, o8 = tid % 8;
      float s = 0.f;
      const float* bp = lws + j * 1152 + o8 * 144;
      for (int i = 0; i < 144; i++) s += bp[i];
      float sb = bbg[t * 8 + o8] * rsqrtf(bbv[t * 8 + o8] + EPS);
      float bfov = sb * tb[t * 8 + o8] + bbb[t * 8 + o8] - bbm[t * 8 + o8] * sb;
      for (int c2 = 0; c2 < 4; c2++) {
        float sa2 = bag[t * 4 + c2] * rsqrtf(bav[t * 4 + c2] + EPS);
        float ha = bab[t * 4 + c2] - bam[t * 4 + c2] * sa2;
        float wsum = 0.f;
        for (int k = 0; k < 9; k++) wsum += tw[((t * 8 + o8) * 4 + c2) * 9 + k];
        bfov += sb * wsum * ha;
      }
      part[tid] = bfov * s;
    }
    __syncthreads();
    if (tid < 9) {
      float acc = lb[t * 9 + tid];
      for (int o8 = 0; o8 < 8; o8++) acc += part[tid * 8 + o8];
      beff[t * 9 + tid] = acc;
    }
  } else if (bi < 576) {
    // -------- conv1 + bias + ReLU + BN1 -> h1 NHWC bf16 (rolling rows) --------
    int b = bi - 64;
    float* xs = (float*)smem;             // [3][32][36]
    float* wsm = (float*)(smem + 13824);  // [64][27]
    {
      const float4* src = (const float4*)(x + (size_t)b * 3072);
      for (int i = tid; i < 768; i += 256) {
        int ic = i >> 8, r = (i >> 3) & 31, v = i & 7;
        *(float4*)(xs + (ic * 32 + r) * 36 + v * 4) = src[i];
      }
      const float4* wsrc = (const float4*)w1;
      float4* wdst = (float4*)wsm;
      for (int i = tid; i < 432; i += 256) wdst[i] = wsrc[i];
    }
    __syncthreads();
    int oc = tid & 63;
    int xg = tid >> 6;
    float wr[27];
#pragma unroll
    for (int q = 0; q < 27; q++) wr[q] = wsm[oc * 27 + q];
    float bias = cb[oc];
    float sc = bg[oc] * rsqrtf(bv[oc] + EPS);
    float sh = bb[oc] - bm[oc] * sc;
    float rx[3][3][12];
    // preload rows 0,1 into slots 0,1
#pragma unroll
    for (int ic = 0; ic < 3; ic++)
#pragma unroll
      for (int s = 0; s < 2; s++) {
        const float* rp = xs + (ic * 32 + s) * 36 + xg * 8;
        float4 A = *(const float4*)rp, B = *(const float4*)(rp + 4), C = *(const float4*)(rp + 8);
        rx[ic][s][0] = A.x; rx[ic][s][1] = A.y; rx[ic][s][2] = A.z; rx[ic][s][3] = A.w;
        rx[ic][s][4] = B.x; rx[ic][s][5] = B.y; rx[ic][s][6] = B.z; rx[ic][s][7] = B.w;
        rx[ic][s][8] = C.x; rx[ic][s][9] = C.y; rx[ic][s][10] = C.z; rx[ic][s][11] = C.w;
      }
    int nst = (xg == 3) ? 6 : 8;
    __hip_bfloat16* dst0 = h1 + (((size_t)b * 30) * 30 + xg * 8) * 64 + oc;
#pragma unroll 1
    for (int y3 = 0; y3 < 10; y3++) {
#pragma unroll
      for (int s = 0; s < 3; s++) {
        int y = y3 * 3 + s;
        int ls = (s + 2) % 3;  // slot receiving row y+2
#pragma unroll
        for (int ic = 0; ic < 3; ic++) {
          const float* rp = xs + (ic * 32 + (y + 2)) * 36 + xg * 8;
          float4 A = *(const float4*)rp, B = *(const float4*)(rp + 4), C = *(const float4*)(rp + 8);
          rx[ic][ls][0] = A.x; rx[ic][ls][1] = A.y; rx[ic][ls][2] = A.z; rx[ic][ls][3] = A.w;
          rx[ic][ls][4] = B.x; rx[ic][ls][5] = B.y; rx[ic][ls][6] = B.z; rx[ic][ls][7] = B.w;
          rx[ic][ls][8] = C.x; rx[ic][ls][9] = C.y; rx[ic][ls][10] = C.z; rx[ic][ls][11] = C.w;
        }
        float o[8];
#pragma unroll
        for (int j = 0; j < 8; j++) o[j] = bias;
#pragma unroll
        for (int ic = 0; ic < 3; ic++)
#pragma unroll
          for (int ky = 0; ky < 3; ky++) {
            int sl = (s + ky) % 3;
#pragma unroll
            for (int kx = 0; kx < 3; kx++) {
              float wv = wr[ic * 9 + ky * 3 + kx];
#pragma unroll
              for (int j = 0; j < 8; j++) o[j] += rx[ic][sl][j + kx] * wv;
            }
          }
        __hip_bfloat16* dst = dst0 + (size_t)y * 30 * 64;
#pragma unroll
        for (int j = 0; j < 8; j++)
          if (j < nst) dst[(size_t)j * 64] = __float2bfloat16(fmaxf(o[j], 0.f) * sc + sh);
      }
    }
  } else if (bi < 1152) {
    // -------- w2s[kk][oc][e'] bf16, e' = e ^ ((oc&7)<<3) --------
    int g = (bi - 576) * 256 + tid;  // < 147456
    int kk = g >> 14;
    int rem = g & 16383;
    int oc = rem >> 6, e = rem & 63;
    int es = e ^ ((oc & 7) << 3);
    w2s[(kk * 256 + oc) * 64 + es] = __float2bfloat16(w2[(oc * 64 + e) * 9 + kk]);
  } else {
    // -------- FC weight bf16 pair packing --------
    int g = (bi - 1152) * 256 + tid;
    {                                // 288 kp x 512 o
      int kp = g >> 9, o = g & 511;
      unsigned int lo = f2bu(fw1[o * 576 + 2 * kp]);
      unsigned int hi = f2bu(fw1[o * 576 + 2 * kp + 1]);
      w1p[g] = lo | (hi << 16);
    }
    if (g < 25600) {                 // 256 kp x 100 o
      int kp = g / 100, o = g % 100;
      unsigned int lo = f2bu(fw2[o * 512 + 2 * kp]);
      unsigned int hi = f2bu(fw2[o * 512 + 2 * kp + 1]);
      w2p[g] = lo | (hi << 16);
    }
  }
}

// ---------------- K2: conv2 implicit GEMM + bias + ReLU + maxpool -> pT ----------------
// grid = 512*14 (b, y-pair). block 512 (8 waves, each 64M x 32N).
__global__ __launch_bounds__(512) void k2_conv2(
    const __hip_bfloat16* __restrict__ h1, const __hip_bfloat16* __restrict__ w2s,
    const float* __restrict__ c2b, __hip_bfloat16* __restrict__ pT) {
  __shared__ __align__(16) char lds[81920];  // A: 2x8KB @0, B: 2x32KB @16384
  int tid = threadIdx.x;
  int bi = blockIdx.x;
  int b = bi / 14, yp = bi % 14;
  int l = tid & 63, w = tid >> 6;

  int r = tid >> 3;
  int rc = r < 56 ? r : 55;
  int yl = rc >= 28 ? 1 : 0;
  int xx = rc - yl * 28;
  int ael = ((tid & 7) << 3) ^ ((rc & 7) << 3);
  const __hip_bfloat16* aSrc0 =
      h1 + (((size_t)(b * 30 + yp * 2 + yl)) * 30 + xx) * 64 + ael;
  const char* bSrc0 = (const char*)w2s;

  f32x4 acc[4][2];
#pragma unroll
  for (int m = 0; m < 4; m++)
#pragma unroll
    for (int n = 0; n < 2; n++) acc[m][n] = (f32x4){0.f, 0.f, 0.f, 0.f};

#define STAGE(kk, s)                                                            \
  {                                                                             \
    g2l16(aSrc0 + (((kk) / 3) * 30 + ((kk) % 3)) * 64,                          \
          lds + (s)*8192 + tid * 16);                                           \
    const char* bs = bSrc0 + (kk)*32768;                                        \
    _Pragma("unroll") for (int q = 0; q < 4; q++)                               \
        g2l16(bs + q * 8192 + tid * 16,                                         \
              lds + 16384 + (s)*32768 + q * 8192 + tid * 16);                   \
  }

  STAGE(0, 0);
#pragma unroll
  for (int c = 0; c < 9; c++) {
    __syncthreads();
    if (c < 8) STAGE(c + 1, (c + 1) & 1);
    char* aB = lds + (c & 1) * 8192;
    char* bB = lds + 16384 + (c & 1) * 32768;
#pragma unroll
    for (int ks = 0; ks < 2; ks++) {
      bf16x8 af[4], bfr[2];
      int kb = (ks * 32 + ((l >> 4) * 8)) * 2;
#pragma unroll
      for (int m = 0; m < 4; m++) {
        int row = m * 16 + (l & 15);
        af[m] = *(const bf16x8*)(aB + row * 128 + (kb ^ ((row & 7) << 4)));
      }
#pragma unroll
      for (int n = 0; n < 2; n++) {
        int oc = w * 32 + n * 16 + (l & 15);
        bfr[n] = *(const bf16x8*)(bB + oc * 128 + (kb ^ ((oc & 7) << 4)));
      }
#pragma unroll
      for (int m = 0; m < 4; m++)
#pragma unroll
        for (int n = 0; n < 2; n++)
          acc[m][n] = __builtin_amdgcn_mfma_f32_16x16x32_bf16(af[m], bfr[n], acc[m][n], 0, 0, 0);
    }
  }
#undef STAGE
  __syncthreads();

  float* ep = (float*)(lds) + w * 2112;  // [64][33] f32 per wave
#pragma unroll
  for (int n = 0; n < 2; n++) {
    int col = n * 16 + (l & 15);
    float bias = c2b[w * 32 + col];
#pragma unroll
    for (int m = 0; m < 4; m++)
#pragma unroll
      for (int i = 0; i < 4; i++) {
        int row = m * 16 + ((l >> 4) * 4) + i;
        ep[row * 33 + col] = fmaxf(acc[m][n][i] + bias, 0.f);
      }
  }
  __syncthreads();
  unsigned short* pool = (unsigned short*)(lds + 69632);  // [256 ch][14 xp]
#pragma unroll
  for (int q = 0; q < 7; q++) {
    int xp = (l >> 5) * 7 + q;
    int col = l & 31;
    int base0 = (2 * xp) * 33 + col;
    float m0 = fmaxf(fmaxf(ep[base0], ep[base0 + 33]),
                     fmaxf(ep[base0 + 28 * 33], ep[base0 + 29 * 33]));
    pool[(w * 32 + col) * 14 + xp] = f2bu(m0);
  }
  __syncthreads();
  if (tid < 448) {  // 64 towers x 7 chunks of 16B
    int t = tid / 7, sub = tid - t * 7;
    union { unsigned short s[8]; uint4 v; } pk;
#pragma unroll
    for (int e = 0; e < 8; e++) {
      int ee = sub * 8 + e;
      pk.s[e] = pool[(t * 4 + (ee & 3)) * 14 + (ee >> 2)];
    }
    *(uint4*)((char*)pT + ((size_t)(t * 512 + b)) * 1568 + yp * 112 + sub * 16) = pk.v;
  }
}

// ---------------- K3: towers z[b,tj] = sum_k pT[t][b][k] * Weff[tj][k] ----------------
__global__ __launch_bounds__(576) void k3_towers(
    const __hip_bfloat16* __restrict__ pT, const float* __restrict__ Weff,
    const float* __restrict__ beff, float* __restrict__ z) {
  __shared__ __align__(16) char sm[131648];
  char* Al = sm;                          // 64 rows x 1616B
  float* Wl = (float*)(sm + 103424);      // 9 x 784 f32
  int tid = threadIdx.x, bi = blockIdx.x;
  int t = bi >> 3, b0 = (bi & 7) * 64;
  for (int idx = tid; idx < 6272; idx += 576) {
    int row = idx / 98, ch = idx - row * 98;
    uint4 v = *(const uint4*)((const char*)pT + ((size_t)(t * 512 + b0 + row)) * 1568 + ch * 16);
    *(uint4*)(Al + row * 1616 + ch * 16) = v;
  }
  const uint4* wsrc = (const uint4*)(Weff + t * 9 * 784);
  for (int idx = tid; idx < 1764; idx += 576) ((uint4*)Wl)[idx] = wsrc[idx];
  __syncthreads();
  int j = tid >> 6, b = tid & 63;
  float acc = 0.f;
  const char* ap = Al + b * 1616;
  const float* wp = Wl + j * 784;
#pragma unroll 2
  for (int ch = 0; ch < 98; ch++) {
    bf16x8 pv = *(const bf16x8*)(ap + ch * 16);
    float4 w0 = *(const float4*)(wp + ch * 8);
    float4 w1_ = *(const float4*)(wp + ch * 8 + 4);
    acc += b2f((unsigned short)pv[0]) * w0.x + b2f((unsigned short)pv[1]) * w0.y +
           b2f((unsigned short)pv[2]) * w0.z + b2f((unsigned short)pv[3]) * w0.w +
           b2f((unsigned short)pv[4]) * w1_.x + b2f((unsigned short)pv[5]) * w1_.y +
           b2f((unsigned short)pv[6]) * w1_.z + b2f((unsigned short)pv[7]) * w1_.w;
  }
  z[(size_t)(b0 + b) * 576 + t * 9 + j] = acc + beff[t * 9 + j];
}

// ---------------- K4: FC1 + ReLU + FC2 fused, one block per batch row ----------------
__global__ __launch_bounds__(256) void k4_fc(
    const float* __restrict__ z, const unsigned int* __restrict__ w1p, const float* __restrict__ b1,
    const unsigned int* __restrict__ w2p, const float* __restrict__ b2, float* __restrict__ out) {
  __shared__ float zl[576];
  __shared__ float hl[512];
  int tid = threadIdx.x, b = blockIdx.x;
  for (int i = tid; i < 576; i += 256) zl[i] = z[(size_t)b * 576 + i];
  __syncthreads();
#pragma unroll
  for (int oo = 0; oo < 2; oo++) {
    int o = tid + oo * 256;
    float acc = b1[o];
#pragma unroll 4
    for (int kp = 0; kp < 288; kp++) {
      unsigned int u = w1p[kp * 512 + o];
      float2 zz = *(const float2*)(zl + 2 * kp);
      acc += zz.x * b2f((unsigned short)(u & 0xffff)) + zz.y * b2f((unsigned short)(u >> 16));
    }
    hl[o] = fmaxf(acc, 0.f);
  }
  __syncthreads();
  if (tid < 100) {
    float acc = b2[tid];
#pragma unroll 4
    for (int kp = 0; kp < 256; kp++) {
      unsigned int u = w2p[kp * 100 + tid];
      float2 hh = *(const float2*)(hl + 2 * kp);
      acc += hh.x * b2f((unsigned short)(u & 0xffff)) + hh.y * b2f((unsigned short)(u >> 16));
    }
    out[(size_t)b * 100 + tid] = acc;
  }
}

// ---------------- launch ----------------
extern "C" void kernel_launch(void* const* d_in, const int* in_sizes, int n_in,
                              void* d_out, int out_size, void* d_ws, size_t ws_size,
                              hipStream_t stream) {
  const float* x    = (const float*)d_in[0];
  const float* w1   = (const float*)d_in[1];
  const float* c1b  = (const float*)d_in[2];
  const float* bn1g = (const float*)d_in[3];
  const float* bn1b = (const float*)d_in[4];
  const float* bn1m = (const float*)d_in[5];
  const float* bn1v = (const float*)d_in[6];
  const float* w2   = (const float*)d_in[7];
  const float* c2b  = (const float*)d_in[8];
  const float* bnag = (const float*)d_in[9];
  const float* bnab = (const float*)d_in[10];
  const float* bnam = (const float*)d_in[11];
  const float* bnav = (const float*)d_in[12];
  const float* tw   = (const float*)d_in[13];
  const float* tb   = (const float*)d_in[14];
  const float* bnbg = (const float*)d_in[15];
  const float* bnbb = (const float*)d_in[16];
  const float* bnbm = (const float*)d_in[17];
  const float* bnbv = (const float*)d_in[18];
  const float* linw = (const float*)d_in[19];
  const float* linb = (const float*)d_in[20];
  const float* fc1w = (const float*)d_in[21];
  const float* fc1b = (const float*)d_in[22];
  const float* fc2w = (const float*)d_in[23];
  const float* fc2b = (const float*)d_in[24];
  float* out = (float*)d_out;

  char* ws = (char*)d_ws;
  size_t off = 0;
  auto alloc = [&](size_t bytes) {
    char* q = ws + off;
    off += (bytes + 255) & ~(size_t)255;
    return q;
  };
  __hip_bfloat16* h1  = (__hip_bfloat16*)alloc(512ull * 30 * 30 * 64 * 2);
  __hip_bfloat16* pT  = (__hip_bfloat16*)alloc(64ull * 512 * 784 * 2 + 256);
  __hip_bfloat16* w2s = (__hip_bfloat16*)alloc(9ull * 256 * 64 * 2);
  float* Weff = (float*)alloc(451584ull * 4);
  float* beff = (float*)alloc(576ull * 4);
  unsigned int* w1p = (unsigned int*)alloc(288ull * 512 * 4);
  unsigned int* w2p = (unsigned int*)alloc(256ull * 100 * 4);
  float* z    = (float*)alloc(512ull * 576 * 4);

  k_prep<<<1728, 256, 0, stream>>>(x, w1, c1b, bn1g, bn1b, bn1m, bn1v, h1,
                                   w2, w2s, fc1w, w1p, fc2w, w2p,
                                   linw, linb, tw, tb,
                                   bnag, bnab, bnam, bnav,
                                   bnbg, bnbb, bnbm, bnbv, Weff, beff);
  k2_conv2<<<512 * 14, 512, 0, stream>>>(h1, w2s, c2b, pT);
  k3_towers<<<512, 576, 0, stream>>>(pT, Weff, beff, z);
  k4_fc<<<512, 256, 0, stream>>>(z, w1p, fc1b, w2p, fc2b, out);
}